// Round 9
// baseline (573.753 us; speedup 1.0000x reference)
//
#include <hip/hip_runtime.h>
#include <math.h>

#define NATOMS 21
#define DESC 210
#define DPAD 224          // padded descriptor count
#define P4 112            // DPAD/2 — float4-packed descriptor pairs
#define NTRAIN 4096
#define NM 128

#define CC 0.0f
#define STDC 1.0f
// q = sqrt(5)/sig
#define QS 0.22360679774997896f
// 5/(3*sig^2)
#define KE 0.016666666666666666f

// async global->LDS, 16B per lane, no VGPR round trip (guide §5 / T3)
__device__ __forceinline__ void gll16(const void* gptr, void* lptr) {
    __builtin_amdgcn_global_load_lds(
        (__attribute__((address_space(1))) void*)gptr,
        (__attribute__((address_space(3))) void*)lptr,
        16, 0, 0);
}

__device__ __forceinline__ void pair_ij(int p, int& i, int& j) {
    int ii = (int)((1.0f + sqrtf(1.0f + 8.0f * (float)p)) * 0.5f);
    while (ii * (ii - 1) / 2 > p) --ii;
    while ((ii + 1) * ii / 2 <= p) ++ii;
    i = ii;
    j = p - ii * (ii - 1) / 2;
}

// prep: blocks [0,448) transpose+pack xs/Jx into bjq (pass1) and xj2 (pass2),
//       accumulate bsq/cj per t; blocks [448,576) build aT, asq.
__global__ __launch_bounds__(256, 2) void k_prep(const float* __restrict__ Rs,
                                                 const float* __restrict__ xs_train,
                                                 const float* __restrict__ Jx,
                                                 float4* __restrict__ bjq,
                                                 float2* __restrict__ xj2,
                                                 float* __restrict__ aT,
                                                 float* __restrict__ asq,
                                                 float* __restrict__ bsqA,
                                                 float* __restrict__ cjA) {
    __shared__ float smem[2 * 32 * 65 + 8];
    const int tid = threadIdx.x;
    const int bid = blockIdx.x;
    if (bid < 448) {
        float* ldsX = smem;
        float* ldsJ = smem + 32 * 65;
        const int bx = bid & 63;        // t tile
        const int by = bid >> 6;        // d tile (0..6)
        const int t0 = bx * 64;
        const int d0 = by * 32;
        #pragma unroll
        for (int k = 0; k < 8; ++k) {
            const int idx = tid + k * 256;        // 64t x 32d
            const int tt = idx >> 5;
            const int dd = idx & 31;
            const int d = d0 + dd;
            float xv = 0.0f, jv = 0.0f;
            if (d < DESC) {
                xv = QS * xs_train[(t0 + tt) * DESC + d];
                jv = Jx[(t0 + tt) * DESC + d];
            }
            ldsX[dd * 65 + tt] = xv;
            ldsJ[dd * 65 + tt] = jv;
        }
        __syncthreads();
        #pragma unroll
        for (int k = 0; k < 4; ++k) {
            const int idx = tid + k * 256;        // 16p x 64t
            const int pp = idx >> 6;
            const int tt = idx & 63;
            float4 v;
            v.x = ldsX[(2 * pp) * 65 + tt];
            v.y = ldsJ[(2 * pp) * 65 + tt];
            v.z = ldsX[(2 * pp + 1) * 65 + tt];
            v.w = ldsJ[(2 * pp + 1) * 65 + tt];
            bjq[(by * 16 + pp) * NTRAIN + t0 + tt] = v;
        }
        // pass2 layout: xj2[t][256] = {q*xs, Jx}
        #pragma unroll
        for (int k = 0; k < 8; ++k) {
            const int idx = tid + k * 256;        // 64t x 32d
            const int tt = idx >> 5;
            const int dd = idx & 31;
            xj2[(t0 + tt) * 256 + d0 + dd] =
                make_float2(ldsX[dd * 65 + tt], ldsJ[dd * 65 + tt]);
        }
        // per-t partials of sum_d b^2 and sum_d b*j over this 32-d tile
        if (tid < 64) {
            float sb = 0.0f, sc = 0.0f;
            #pragma unroll
            for (int dd = 0; dd < 32; ++dd) {
                const float b = ldsX[dd * 65 + tid];
                const float jj = ldsJ[dd * 65 + tid];
                sb = fmaf(b, b, sb);
                sc = fmaf(b, jj, sc);
            }
            atomicAdd(&bsqA[t0 + tid], sb);
            atomicAdd(&cjA[t0 + tid], sc);
        }
    } else {
        const int m = bid - 448;
        float* R = smem;
        float* red = smem + 64;
        if (tid < NATOMS * 3) R[tid] = Rs[m * NATOMS * 3 + tid];
        __syncthreads();
        float a2 = 0.0f;
        if (tid < DPAD) {
            float a = 0.0f;
            if (tid < DESC) {
                int i, j;
                pair_ij(tid, i, j);
                const float dx = R[i * 3 + 0] - R[j * 3 + 0];
                const float dy = R[i * 3 + 1] - R[j * 3 + 1];
                const float dz = R[i * 3 + 2] - R[j * 3 + 2];
                a = QS / sqrtf(dx * dx + dy * dy + dz * dz);
            }
            aT[tid * NM + m] = a;
            a2 = a * a;
        }
        #pragma unroll
        for (int off = 32; off > 0; off >>= 1) a2 += __shfl_down(a2, off, 64);
        if ((tid & 63) == 0) red[tid >> 6] = a2;
        __syncthreads();
        if (tid == 0) asq[m] = red[0] + red[1] + red[2] + red[3];
    }
}

// pass 1: 64 t x 16 m per block. Counted-vmcnt 3-buffer pipeline (T3+T4):
// per chunk: wait vmcnt(4) (oldest chunk only) -> raw barrier -> sched fence ->
// compute -> issue chunk c+2. Next chunk's 4 loads stay in flight across the
// barrier. Issue-after-compute makes 3 buffers race-free (all waves past
// barrier_c have finished compute c-1).
__global__ __launch_bounds__(256, 2) void k_pass1(const float4* __restrict__ bjq,
                                                  const float* __restrict__ aT,
                                                  const float* __restrict__ asq,
                                                  const float* __restrict__ bsqA,
                                                  const float* __restrict__ cjA,
                                                  float2* __restrict__ w12,
                                                  float* __restrict__ EsAcc,
                                                  float* __restrict__ S1) {
    const int tid = threadIdx.x;
    const int bid = blockIdx.x;
    const int bx = (bid & 7) + 8 * (bid >> 6);   // t-tile 0..63
    const int my = (bid >> 3) & 7;               // m-group 0..7
    const int t0 = bx * 64;
    const int m0 = my * 16;
    const int t = tid & 63;
    const int mq = tid >> 6;                     // 0..3, wave-uniform

    __shared__ __align__(16) float aS[P4][32];          // 14 KB
    __shared__ __align__(16) float4 bjS[3][16][64];     // 48 KB

    #pragma unroll
    for (int k = 0; k < 14; ++k) {
        const int idx = tid + k * 256;   // 112*32 = 3584
        const int p = idx >> 5;
        const int c = idx & 31;
        aS[p][c] = aT[(2 * p + (c >> 4)) * NM + m0 + (c & 15)];
    }
    // prologue: stage chunks 0 and 1 (4 gll16 each; vmcnt = 8)
    #pragma unroll
    for (int k = 0; k < 4; ++k) {
        const int idx = tid + k * 256;
        const int row = idx >> 6;        // wave-uniform
        const int col = idx & 63;
        gll16(&bjq[row * NTRAIN + t0 + col], &bjS[0][row][col]);
    }
    #pragma unroll
    for (int k = 0; k < 4; ++k) {
        const int idx = tid + k * 256;
        const int row = idx >> 6;
        const int col = idx & 63;
        gll16(&bjq[(16 + row) * NTRAIN + t0 + col], &bjS[1][row][col]);
    }

    float P[4] = {0.f, 0.f, 0.f, 0.f};
    float Q[4] = {0.f, 0.f, 0.f, 0.f};

    #pragma unroll
    for (int c = 0; c < 7; ++c) {
        // wait for the OLDEST outstanding chunk only; chunk c+1 stays in flight.
        if (c < 6) {
            asm volatile("s_waitcnt vmcnt(4) lgkmcnt(0)" ::: "memory");
        } else {
            asm volatile("s_waitcnt vmcnt(0) lgkmcnt(0)" ::: "memory");
        }
        __builtin_amdgcn_s_barrier();
        __builtin_amdgcn_sched_barrier(0);
        #pragma unroll
        for (int u = 0; u < 16; ++u) {
            const int p = c * 16 + u;
            const float4 bj = bjS[c % 3][u][t];
            const float4 aA = *reinterpret_cast<const float4*>(&aS[p][mq * 4]);
            const float4 aB = *reinterpret_cast<const float4*>(&aS[p][16 + mq * 4]);
            P[0] = fmaf(aA.x, bj.x, P[0]); P[1] = fmaf(aA.y, bj.x, P[1]);
            P[2] = fmaf(aA.z, bj.x, P[2]); P[3] = fmaf(aA.w, bj.x, P[3]);
            Q[0] = fmaf(aA.x, bj.y, Q[0]); Q[1] = fmaf(aA.y, bj.y, Q[1]);
            Q[2] = fmaf(aA.z, bj.y, Q[2]); Q[3] = fmaf(aA.w, bj.y, Q[3]);
            P[0] = fmaf(aB.x, bj.z, P[0]); P[1] = fmaf(aB.y, bj.z, P[1]);
            P[2] = fmaf(aB.z, bj.z, P[2]); P[3] = fmaf(aB.w, bj.z, P[3]);
            Q[0] = fmaf(aB.x, bj.w, Q[0]); Q[1] = fmaf(aB.y, bj.w, Q[1]);
            Q[2] = fmaf(aB.z, bj.w, Q[2]); Q[3] = fmaf(aB.w, bj.w, Q[3]);
        }
        if (c + 2 < 7) {
            #pragma unroll
            for (int k = 0; k < 4; ++k) {
                const int idx = tid + k * 256;
                const int row = idx >> 6;
                const int col = idx & 63;
                gll16(&bjq[((c + 2) * 16 + row) * NTRAIN + t0 + col],
                      &bjS[(c + 2) % 3][row][col]);
            }
        }
    }

    const float bsqv = bsqA[t0 + t];
    const float cjv = cjA[t0 + t];
    float esv[4], s1v[4];
    #pragma unroll
    for (int i = 0; i < 4; ++i) {
        const int m = m0 + mq * 4 + i;
        float dist2 = asq[m] + bsqv - 2.0f * P[i];
        dist2 = fmaxf(dist2, 0.0f);
        const float x = sqrtf(dist2);
        const float e = KE * expf(-x);
        const float dotv = Q[i] - cjv;
        const float w1v = e * dotv;
        const float w2v = e * (1.0f + x);
        w12[m * NTRAIN + t0 + t] = make_float2(w1v, w2v);
        esv[i] = w2v * dotv;
        s1v[i] = w1v;
    }
    #pragma unroll
    for (int off = 32; off > 0; off >>= 1) {
        #pragma unroll
        for (int i = 0; i < 4; ++i) {
            esv[i] += __shfl_down(esv[i], off, 64);
            s1v[i] += __shfl_down(s1v[i], off, 64);
        }
    }
    if ((tid & 63) == 0) {
        #pragma unroll
        for (int i = 0; i < 4; ++i) {
            atomicAdd(&EsAcc[m0 + mq * 4 + i], esv[i]);
            atomicAdd(&S1[m0 + mq * 4 + i], s1v[i]);
        }
    }
}

// pass 2: same counted-vmcnt 3-buffer pipeline. 256 threads (d = tid), 8 m,
// t-chunk 128 in 16 sub-chunks of 8 t.
__global__ __launch_bounds__(256, 2) void k_pass2(const float2* __restrict__ xj2,
                                                  const float2* __restrict__ w12,
                                                  float* __restrict__ F1acc,
                                                  float* __restrict__ F2acc) {
    const int tid = threadIdx.x;
    const int bid = blockIdx.x;
    const int bx = (bid & 7) + 8 * (bid >> 7);   // t-tile 0..31
    const int my = (bid >> 3) & 15;              // m-group 0..15
    const int t0 = bx * 128;
    const int m0 = my * 8;

    __shared__ __align__(16) float2 wS[8][128];        // 8 KB  [mi][tt]
    __shared__ __align__(16) float2 xjS[3][8][256];    // 48 KB [buf][tt][d]

    // prologue: stage w-tile (2 gll16) + chunks 0,1 (4 gll16 each) -> vmcnt 10
    #pragma unroll
    for (int k = 0; k < 2; ++k) {
        const int idx = tid + k * 256;
        const int mi = idx >> 6;          // wave-uniform per 64-lane group
        const int c16 = idx & 63;
        gll16(&w12[(m0 + mi) * NTRAIN + t0 + 2 * c16], &wS[mi][2 * c16]);
    }
    #pragma unroll
    for (int k = 0; k < 4; ++k) {
        const int idx = tid + k * 256;
        const int row = idx >> 7;
        const int col = idx & 127;
        gll16(&xj2[(t0 + row) * 256 + 2 * col], &xjS[0][row][2 * col]);
    }
    #pragma unroll
    for (int k = 0; k < 4; ++k) {
        const int idx = tid + k * 256;
        const int row = idx >> 7;
        const int col = idx & 127;
        gll16(&xj2[(t0 + 8 + row) * 256 + 2 * col], &xjS[1][row][2 * col]);
    }

    const int d = (tid < DESC) ? tid : 0;
    float G1[8] = {0.f, 0.f, 0.f, 0.f, 0.f, 0.f, 0.f, 0.f};
    float G2[8] = {0.f, 0.f, 0.f, 0.f, 0.f, 0.f, 0.f, 0.f};

    #pragma unroll
    for (int c = 0; c < 16; ++c) {
        if (c < 15) {
            asm volatile("s_waitcnt vmcnt(4) lgkmcnt(0)" ::: "memory");
        } else {
            asm volatile("s_waitcnt vmcnt(0) lgkmcnt(0)" ::: "memory");
        }
        __builtin_amdgcn_s_barrier();
        __builtin_amdgcn_sched_barrier(0);
        #pragma unroll
        for (int tp = 0; tp < 4; ++tp) {
            const int tb = c * 8 + tp * 2;
            float4 w0 = *reinterpret_cast<const float4*>(&wS[0][tb]);
            float4 w1 = *reinterpret_cast<const float4*>(&wS[1][tb]);
            float4 w2 = *reinterpret_cast<const float4*>(&wS[2][tb]);
            float4 w3 = *reinterpret_cast<const float4*>(&wS[3][tb]);
            float4 w4 = *reinterpret_cast<const float4*>(&wS[4][tb]);
            float4 w5 = *reinterpret_cast<const float4*>(&wS[5][tb]);
            float4 w6 = *reinterpret_cast<const float4*>(&wS[6][tb]);
            float4 w7 = *reinterpret_cast<const float4*>(&wS[7][tb]);
            const float2 xj0 = xjS[c % 3][tp * 2][d];
            const float2 xj1 = xjS[c % 3][tp * 2 + 1][d];
            G1[0] = fmaf(w0.x, xj0.x, G1[0]); G2[0] = fmaf(w0.y, xj0.y, G2[0]);
            G1[0] = fmaf(w0.z, xj1.x, G1[0]); G2[0] = fmaf(w0.w, xj1.y, G2[0]);
            G1[1] = fmaf(w1.x, xj0.x, G1[1]); G2[1] = fmaf(w1.y, xj0.y, G2[1]);
            G1[1] = fmaf(w1.z, xj1.x, G1[1]); G2[1] = fmaf(w1.w, xj1.y, G2[1]);
            G1[2] = fmaf(w2.x, xj0.x, G1[2]); G2[2] = fmaf(w2.y, xj0.y, G2[2]);
            G1[2] = fmaf(w2.z, xj1.x, G1[2]); G2[2] = fmaf(w2.w, xj1.y, G2[2]);
            G1[3] = fmaf(w3.x, xj0.x, G1[3]); G2[3] = fmaf(w3.y, xj0.y, G2[3]);
            G1[3] = fmaf(w3.z, xj1.x, G1[3]); G2[3] = fmaf(w3.w, xj1.y, G2[3]);
            G1[4] = fmaf(w4.x, xj0.x, G1[4]); G2[4] = fmaf(w4.y, xj0.y, G2[4]);
            G1[4] = fmaf(w4.z, xj1.x, G1[4]); G2[4] = fmaf(w4.w, xj1.y, G2[4]);
            G1[5] = fmaf(w5.x, xj0.x, G1[5]); G2[5] = fmaf(w5.y, xj0.y, G2[5]);
            G1[5] = fmaf(w5.z, xj1.x, G1[5]); G2[5] = fmaf(w5.w, xj1.y, G2[5]);
            G1[6] = fmaf(w6.x, xj0.x, G1[6]); G2[6] = fmaf(w6.y, xj0.y, G2[6]);
            G1[6] = fmaf(w6.z, xj1.x, G1[6]); G2[6] = fmaf(w6.w, xj1.y, G2[6]);
            G1[7] = fmaf(w7.x, xj0.x, G1[7]); G2[7] = fmaf(w7.y, xj0.y, G2[7]);
            G1[7] = fmaf(w7.z, xj1.x, G1[7]); G2[7] = fmaf(w7.w, xj1.y, G2[7]);
        }
        if (c + 2 < 16) {
            #pragma unroll
            for (int k = 0; k < 4; ++k) {
                const int idx = tid + k * 256;
                const int row = idx >> 7;
                const int col = idx & 127;
                gll16(&xj2[(t0 + (c + 2) * 8 + row) * 256 + 2 * col],
                      &xjS[(c + 2) % 3][row][2 * col]);
            }
        }
    }

    if (tid < DESC) {
        #pragma unroll
        for (int mi = 0; mi < 8; ++mi) {
            atomicAdd(&F1acc[(m0 + mi) * DESC + tid], G1[mi]);
            atomicAdd(&F2acc[(m0 + mi) * DESC + tid], G2[mi]);
        }
    }
}

// final assembly — coef, force scatter, Es
__global__ __launch_bounds__(256) void k_final(const float* __restrict__ Rs,
                                               const float* __restrict__ aT,
                                               const float* __restrict__ S1,
                                               const float* __restrict__ EsAcc,
                                               const float* __restrict__ F1acc,
                                               const float* __restrict__ F2acc,
                                               float* __restrict__ out) {
    const int m = blockIdx.x;
    __shared__ float R[NATOMS * 3];
    __shared__ float FsL[NATOMS * 3];
    const int tid = threadIdx.x;
    if (tid < NATOMS * 3) {
        R[tid] = Rs[m * NATOMS * 3 + tid];
        FsL[tid] = 0.0f;
    }
    __syncthreads();
    if (tid < DESC) {
        int i, j;
        pair_ij(tid, i, j);
        const float dx = R[i * 3 + 0] - R[j * 3 + 0];
        const float dy = R[i * 3 + 1] - R[j * 3 + 1];
        const float dz = R[i * 3 + 2] - R[j * 3 + 2];
        const float r2 = dx * dx + dy * dy + dz * dz;
        const float rinv = 1.0f / sqrtf(r2);
        const float a = aT[tid * NM + m];  // q/r
        const float F1 = a * S1[m] - F1acc[m * DESC + tid];
        const float Fx = (F1 - F2acc[m * DESC + tid]) * STDC;
        const float coef = Fx * (rinv * rinv * rinv);
        atomicAdd(&FsL[j * 3 + 0], coef * dx);
        atomicAdd(&FsL[j * 3 + 1], coef * dy);
        atomicAdd(&FsL[j * 3 + 2], coef * dz);
        atomicAdd(&FsL[i * 3 + 0], -coef * dx);
        atomicAdd(&FsL[i * 3 + 1], -coef * dy);
        atomicAdd(&FsL[i * 3 + 2], -coef * dz);
    }
    __syncthreads();
    if (tid < NATOMS * 3) out[NM + m * NATOMS * 3 + tid] = FsL[tid];
    if (tid == 0) out[m] = CC + (EsAcc[m] / QS) * STDC;
}

extern "C" void kernel_launch(void* const* d_in, const int* in_sizes, int n_in,
                              void* d_out, int out_size, void* d_ws, size_t ws_size,
                              hipStream_t stream) {
    const float* Rs = (const float*)d_in[0];
    const float* xs_train = (const float*)d_in[1];
    const float* Jx = (const float*)d_in[2];
    float* out = (float*)d_out;
    float* ws = (float*)d_ws;

    // zeroed prefix
    float* F1acc = ws;                         // 26880
    float* F2acc = ws + 26880;                 // 26880
    float* EsAcc = ws + 53760;                 // 128
    float* S1 = ws + 53888;                    // 128
    float* bsqA = ws + 54016;                  // 4096
    float* cjA = ws + 58112;                   // 4096  -> zero block ends at 62208
    // non-zeroed
    float* aT = ws + 62208;                    // 224*128 = 28672
    float* asq = ws + 90880;                   // 128
    float4* bjq = (float4*)(ws + 91008);       // 112*4096 float4 (16B aligned)
    float2* w12 = (float2*)(ws + 1926016);     // 128*4096 float2 (16B aligned)
    float2* xj2 = (float2*)(ws + 2974592);     // 4096*256 float2 (16B aligned)
    // end 5071744 floats (~20.3 MB)

    hipMemsetAsync(ws, 0, (size_t)62208 * sizeof(float), stream);

    k_prep<<<576, 256, 0, stream>>>(Rs, xs_train, Jx, bjq, xj2, aT, asq, bsqA, cjA);
    k_pass1<<<512, 256, 0, stream>>>(bjq, aT, asq, bsqA, cjA, w12, EsAcc, S1);
    k_pass2<<<512, 256, 0, stream>>>(xj2, w12, F1acc, F2acc);
    k_final<<<NM, 256, 0, stream>>>(Rs, aT, S1, EsAcc, F1acc, F2acc, out);
}

// Round 10
// 78.310 us; speedup vs baseline: 7.3267x; 7.3267x over previous
//
#include <hip/hip_runtime.h>
#include <math.h>

#define NATOMS 21
#define DESC 210
#define DPAD 224          // padded descriptor count
#define P4 112            // DPAD/2 — float4-packed descriptor pairs
#define NTRAIN 4096
#define NM 128

#define CC 0.0f
#define STDC 1.0f
// q = sqrt(5)/sig
#define QS 0.22360679774997896f
// 5/(3*sig^2)
#define KE 0.016666666666666666f

// async global->LDS, 16B per lane, no VGPR round trip (guide §5 / T3)
__device__ __forceinline__ void gll16(const void* gptr, void* lptr) {
    __builtin_amdgcn_global_load_lds(
        (__attribute__((address_space(1))) void*)gptr,
        (__attribute__((address_space(3))) void*)lptr,
        16, 0, 0);
}

__device__ __forceinline__ void pair_ij(int p, int& i, int& j) {
    int ii = (int)((1.0f + sqrtf(1.0f + 8.0f * (float)p)) * 0.5f);
    while (ii * (ii - 1) / 2 > p) --ii;
    while ((ii + 1) * ii / 2 <= p) ++ii;
    i = ii;
    j = p - ii * (ii - 1) / 2;
}

// prep: blocks [0,448) transpose+pack xs/Jx into bjq (pass1) and xj2 (pass2),
//       accumulate bsq/cj per t; blocks [448,576) build aT, asq.
__global__ __launch_bounds__(256, 2) void k_prep(const float* __restrict__ Rs,
                                                 const float* __restrict__ xs_train,
                                                 const float* __restrict__ Jx,
                                                 float4* __restrict__ bjq,
                                                 float2* __restrict__ xj2,
                                                 float* __restrict__ aT,
                                                 float* __restrict__ asq,
                                                 float* __restrict__ bsqA,
                                                 float* __restrict__ cjA) {
    __shared__ float smem[2 * 32 * 65 + 8];
    const int tid = threadIdx.x;
    const int bid = blockIdx.x;
    if (bid < 448) {
        float* ldsX = smem;
        float* ldsJ = smem + 32 * 65;
        const int bx = bid & 63;        // t tile
        const int by = bid >> 6;        // d tile (0..6)
        const int t0 = bx * 64;
        const int d0 = by * 32;
        #pragma unroll
        for (int k = 0; k < 8; ++k) {
            const int idx = tid + k * 256;        // 64t x 32d
            const int tt = idx >> 5;
            const int dd = idx & 31;
            const int d = d0 + dd;
            float xv = 0.0f, jv = 0.0f;
            if (d < DESC) {
                xv = QS * xs_train[(t0 + tt) * DESC + d];
                jv = Jx[(t0 + tt) * DESC + d];
            }
            ldsX[dd * 65 + tt] = xv;
            ldsJ[dd * 65 + tt] = jv;
        }
        __syncthreads();
        #pragma unroll
        for (int k = 0; k < 4; ++k) {
            const int idx = tid + k * 256;        // 16p x 64t
            const int pp = idx >> 6;
            const int tt = idx & 63;
            float4 v;
            v.x = ldsX[(2 * pp) * 65 + tt];
            v.y = ldsJ[(2 * pp) * 65 + tt];
            v.z = ldsX[(2 * pp + 1) * 65 + tt];
            v.w = ldsJ[(2 * pp + 1) * 65 + tt];
            bjq[(by * 16 + pp) * NTRAIN + t0 + tt] = v;
        }
        // pass2 layout: xj2[t][256] = {q*xs, Jx}
        #pragma unroll
        for (int k = 0; k < 8; ++k) {
            const int idx = tid + k * 256;        // 64t x 32d
            const int tt = idx >> 5;
            const int dd = idx & 31;
            xj2[(t0 + tt) * 256 + d0 + dd] =
                make_float2(ldsX[dd * 65 + tt], ldsJ[dd * 65 + tt]);
        }
        // per-t partials of sum_d b^2 and sum_d b*j over this 32-d tile
        if (tid < 64) {
            float sb = 0.0f, sc = 0.0f;
            #pragma unroll
            for (int dd = 0; dd < 32; ++dd) {
                const float b = ldsX[dd * 65 + tid];
                const float jj = ldsJ[dd * 65 + tid];
                sb = fmaf(b, b, sb);
                sc = fmaf(b, jj, sc);
            }
            atomicAdd(&bsqA[t0 + tid], sb);
            atomicAdd(&cjA[t0 + tid], sc);
        }
    } else {
        const int m = bid - 448;
        float* R = smem;
        float* red = smem + 64;
        if (tid < NATOMS * 3) R[tid] = Rs[m * NATOMS * 3 + tid];
        __syncthreads();
        float a2 = 0.0f;
        if (tid < DPAD) {
            float a = 0.0f;
            if (tid < DESC) {
                int i, j;
                pair_ij(tid, i, j);
                const float dx = R[i * 3 + 0] - R[j * 3 + 0];
                const float dy = R[i * 3 + 1] - R[j * 3 + 1];
                const float dz = R[i * 3 + 2] - R[j * 3 + 2];
                a = QS / sqrtf(dx * dx + dy * dy + dz * dz);
            }
            aT[tid * NM + m] = a;
            a2 = a * a;
        }
        #pragma unroll
        for (int off = 32; off > 0; off >>= 1) a2 += __shfl_down(a2, off, 64);
        if ((tid & 63) == 0) red[tid >> 6] = a2;
        __syncthreads();
        if (tid == 0) asq[m] = red[0] + red[1] + red[2] + red[3];
    }
}

// pass 1: 64 t x 16 m per block. Counted-vmcnt 3-buffer pipeline (T3+T4),
// chunk loop ROLLED (R9 lesson: full unroll -> VGPR cap -> 1 GB scratch).
// Per chunk: wait vmcnt(4) (drains oldest chunk only) -> raw barrier ->
// sched fence -> compute -> issue chunk c+2.
__global__ __launch_bounds__(256, 2) void k_pass1(const float4* __restrict__ bjq,
                                                  const float* __restrict__ aT,
                                                  const float* __restrict__ asq,
                                                  const float* __restrict__ bsqA,
                                                  const float* __restrict__ cjA,
                                                  float2* __restrict__ w12,
                                                  float* __restrict__ EsAcc,
                                                  float* __restrict__ S1) {
    const int tid = threadIdx.x;
    const int bid = blockIdx.x;
    const int bx = (bid & 7) + 8 * (bid >> 6);   // t-tile 0..63
    const int my = (bid >> 3) & 7;               // m-group 0..7
    const int t0 = bx * 64;
    const int m0 = my * 16;
    const int t = tid & 63;
    const int mq = tid >> 6;                     // 0..3, wave-uniform

    __shared__ __align__(16) float aS[P4][32];          // 14 KB
    __shared__ __align__(16) float4 bjS[3][16][64];     // 48 KB

    #pragma unroll
    for (int k = 0; k < 14; ++k) {
        const int idx = tid + k * 256;   // 112*32 = 3584
        const int p = idx >> 5;
        const int c = idx & 31;
        aS[p][c] = aT[(2 * p + (c >> 4)) * NM + m0 + (c & 15)];
    }
    // prologue: stage chunks 0 and 1 (4 gll16 each; 8 outstanding)
    {
        const int row = tid >> 6;        // wave-uniform
        const int col = tid & 63;
        #pragma unroll
        for (int k = 0; k < 4; ++k)
            gll16(&bjq[(row + 4 * k) * NTRAIN + t0 + col], &bjS[0][row + 4 * k][col]);
        #pragma unroll
        for (int k = 0; k < 4; ++k)
            gll16(&bjq[(16 + row + 4 * k) * NTRAIN + t0 + col],
                  &bjS[1][row + 4 * k][col]);
    }

    float P[4] = {0.f, 0.f, 0.f, 0.f};
    float Q[4] = {0.f, 0.f, 0.f, 0.f};

    for (int c = 0; c < 7; ++c) {
        if (c < 6) {
            asm volatile("s_waitcnt vmcnt(4) lgkmcnt(0)" ::: "memory");
        } else {
            asm volatile("s_waitcnt vmcnt(0) lgkmcnt(0)" ::: "memory");
        }
        __builtin_amdgcn_s_barrier();
        __builtin_amdgcn_sched_barrier(0);
        const float4* bjC = &bjS[c % 3][0][0];
        const float* aC = &aS[c * 16][0];
        #pragma unroll
        for (int u = 0; u < 16; ++u) {
            const float4 bj = bjC[u * 64 + t];
            const float4 aA = *reinterpret_cast<const float4*>(aC + u * 32 + mq * 4);
            const float4 aB = *reinterpret_cast<const float4*>(aC + u * 32 + 16 + mq * 4);
            P[0] = fmaf(aA.x, bj.x, P[0]); P[1] = fmaf(aA.y, bj.x, P[1]);
            P[2] = fmaf(aA.z, bj.x, P[2]); P[3] = fmaf(aA.w, bj.x, P[3]);
            Q[0] = fmaf(aA.x, bj.y, Q[0]); Q[1] = fmaf(aA.y, bj.y, Q[1]);
            Q[2] = fmaf(aA.z, bj.y, Q[2]); Q[3] = fmaf(aA.w, bj.y, Q[3]);
            P[0] = fmaf(aB.x, bj.z, P[0]); P[1] = fmaf(aB.y, bj.z, P[1]);
            P[2] = fmaf(aB.z, bj.z, P[2]); P[3] = fmaf(aB.w, bj.z, P[3]);
            Q[0] = fmaf(aB.x, bj.w, Q[0]); Q[1] = fmaf(aB.y, bj.w, Q[1]);
            Q[2] = fmaf(aB.z, bj.w, Q[2]); Q[3] = fmaf(aB.w, bj.w, Q[3]);
        }
        if (c < 5) {
            const int row = tid >> 6;
            const int col = tid & 63;
            float4* dst = &bjS[(c + 2) % 3][0][0];
            const float4* src = &bjq[(c + 2) * 16 * NTRAIN + t0 + col];
            #pragma unroll
            for (int k = 0; k < 4; ++k)
                gll16(&src[(row + 4 * k) * NTRAIN], &dst[(row + 4 * k) * 64 + col]);
        }
    }

    const float bsqv = bsqA[t0 + t];
    const float cjv = cjA[t0 + t];
    float esv[4], s1v[4];
    #pragma unroll
    for (int i = 0; i < 4; ++i) {
        const int m = m0 + mq * 4 + i;
        float dist2 = asq[m] + bsqv - 2.0f * P[i];
        dist2 = fmaxf(dist2, 0.0f);
        const float x = sqrtf(dist2);
        const float e = KE * expf(-x);
        const float dotv = Q[i] - cjv;
        const float w1v = e * dotv;
        const float w2v = e * (1.0f + x);
        w12[m * NTRAIN + t0 + t] = make_float2(w1v, w2v);
        esv[i] = w2v * dotv;
        s1v[i] = w1v;
    }
    #pragma unroll
    for (int off = 32; off > 0; off >>= 1) {
        #pragma unroll
        for (int i = 0; i < 4; ++i) {
            esv[i] += __shfl_down(esv[i], off, 64);
            s1v[i] += __shfl_down(s1v[i], off, 64);
        }
    }
    if ((tid & 63) == 0) {
        #pragma unroll
        for (int i = 0; i < 4; ++i) {
            atomicAdd(&EsAcc[m0 + mq * 4 + i], esv[i]);
            atomicAdd(&S1[m0 + mq * 4 + i], s1v[i]);
        }
    }
}

// pass 2: same counted-vmcnt 3-buffer pipeline, chunk loop ROLLED.
// 256 threads (d = tid), 8 m, t-chunk 128 in 16 sub-chunks of 8 t.
__global__ __launch_bounds__(256, 2) void k_pass2(const float2* __restrict__ xj2,
                                                  const float2* __restrict__ w12,
                                                  float* __restrict__ F1acc,
                                                  float* __restrict__ F2acc) {
    const int tid = threadIdx.x;
    const int bid = blockIdx.x;
    const int bx = (bid & 7) + 8 * (bid >> 7);   // t-tile 0..31
    const int my = (bid >> 3) & 15;              // m-group 0..15
    const int t0 = bx * 128;
    const int m0 = my * 8;

    __shared__ __align__(16) float2 wS[8][128];        // 8 KB  [mi][tt]
    __shared__ __align__(16) float2 xjS[3][8][256];    // 48 KB [buf][tt][d]

    // prologue: w-tile (2 gll16) + chunks 0,1 (4 gll16 each) -> 10 outstanding
    {
        const int mi = tid >> 6;          // wave-uniform
        const int c16 = tid & 63;
        gll16(&w12[(m0 + mi) * NTRAIN + t0 + 2 * c16], &wS[mi][2 * c16]);
        gll16(&w12[(m0 + 4 + mi) * NTRAIN + t0 + 2 * c16], &wS[4 + mi][2 * c16]);
        const int row = tid >> 7;
        const int col = tid & 127;
        #pragma unroll
        for (int k = 0; k < 4; ++k)
            gll16(&xj2[(t0 + row + 2 * k) * 256 + 2 * col],
                  &xjS[0][row + 2 * k][2 * col]);
        #pragma unroll
        for (int k = 0; k < 4; ++k)
            gll16(&xj2[(t0 + 8 + row + 2 * k) * 256 + 2 * col],
                  &xjS[1][row + 2 * k][2 * col]);
    }

    const int d = (tid < DESC) ? tid : 0;
    float G1[8] = {0.f, 0.f, 0.f, 0.f, 0.f, 0.f, 0.f, 0.f};
    float G2[8] = {0.f, 0.f, 0.f, 0.f, 0.f, 0.f, 0.f, 0.f};

    for (int c = 0; c < 16; ++c) {
        if (c < 15) {
            asm volatile("s_waitcnt vmcnt(4) lgkmcnt(0)" ::: "memory");
        } else {
            asm volatile("s_waitcnt vmcnt(0) lgkmcnt(0)" ::: "memory");
        }
        __builtin_amdgcn_s_barrier();
        __builtin_amdgcn_sched_barrier(0);
        const float2* xjC = &xjS[c % 3][0][0];
        #pragma unroll
        for (int tp = 0; tp < 4; ++tp) {
            const int tb = c * 8 + tp * 2;
            float4 w0 = *reinterpret_cast<const float4*>(&wS[0][tb]);
            float4 w1 = *reinterpret_cast<const float4*>(&wS[1][tb]);
            float4 w2 = *reinterpret_cast<const float4*>(&wS[2][tb]);
            float4 w3 = *reinterpret_cast<const float4*>(&wS[3][tb]);
            float4 w4 = *reinterpret_cast<const float4*>(&wS[4][tb]);
            float4 w5 = *reinterpret_cast<const float4*>(&wS[5][tb]);
            float4 w6 = *reinterpret_cast<const float4*>(&wS[6][tb]);
            float4 w7 = *reinterpret_cast<const float4*>(&wS[7][tb]);
            const float2 xj0 = xjC[(tp * 2) * 256 + d];
            const float2 xj1 = xjC[(tp * 2 + 1) * 256 + d];
            G1[0] = fmaf(w0.x, xj0.x, G1[0]); G2[0] = fmaf(w0.y, xj0.y, G2[0]);
            G1[0] = fmaf(w0.z, xj1.x, G1[0]); G2[0] = fmaf(w0.w, xj1.y, G2[0]);
            G1[1] = fmaf(w1.x, xj0.x, G1[1]); G2[1] = fmaf(w1.y, xj0.y, G2[1]);
            G1[1] = fmaf(w1.z, xj1.x, G1[1]); G2[1] = fmaf(w1.w, xj1.y, G2[1]);
            G1[2] = fmaf(w2.x, xj0.x, G1[2]); G2[2] = fmaf(w2.y, xj0.y, G2[2]);
            G1[2] = fmaf(w2.z, xj1.x, G1[2]); G2[2] = fmaf(w2.w, xj1.y, G2[2]);
            G1[3] = fmaf(w3.x, xj0.x, G1[3]); G2[3] = fmaf(w3.y, xj0.y, G2[3]);
            G1[3] = fmaf(w3.z, xj1.x, G1[3]); G2[3] = fmaf(w3.w, xj1.y, G2[3]);
            G1[4] = fmaf(w4.x, xj0.x, G1[4]); G2[4] = fmaf(w4.y, xj0.y, G2[4]);
            G1[4] = fmaf(w4.z, xj1.x, G1[4]); G2[4] = fmaf(w4.w, xj1.y, G2[4]);
            G1[5] = fmaf(w5.x, xj0.x, G1[5]); G2[5] = fmaf(w5.y, xj0.y, G2[5]);
            G1[5] = fmaf(w5.z, xj1.x, G1[5]); G2[5] = fmaf(w5.w, xj1.y, G2[5]);
            G1[6] = fmaf(w6.x, xj0.x, G1[6]); G2[6] = fmaf(w6.y, xj0.y, G2[6]);
            G1[6] = fmaf(w6.z, xj1.x, G1[6]); G2[6] = fmaf(w6.w, xj1.y, G2[6]);
            G1[7] = fmaf(w7.x, xj0.x, G1[7]); G2[7] = fmaf(w7.y, xj0.y, G2[7]);
            G1[7] = fmaf(w7.z, xj1.x, G1[7]); G2[7] = fmaf(w7.w, xj1.y, G2[7]);
        }
        if (c < 14) {
            const int row = tid >> 7;
            const int col = tid & 127;
            float2* dst = &xjS[(c + 2) % 3][0][0];
            #pragma unroll
            for (int k = 0; k < 4; ++k)
                gll16(&xj2[(t0 + (c + 2) * 8 + row + 2 * k) * 256 + 2 * col],
                      &dst[(row + 2 * k) * 256 + 2 * col]);
        }
    }

    if (tid < DESC) {
        #pragma unroll
        for (int mi = 0; mi < 8; ++mi) {
            atomicAdd(&F1acc[(m0 + mi) * DESC + tid], G1[mi]);
            atomicAdd(&F2acc[(m0 + mi) * DESC + tid], G2[mi]);
        }
    }
}

// final assembly — coef, force scatter, Es
__global__ __launch_bounds__(256) void k_final(const float* __restrict__ Rs,
                                               const float* __restrict__ aT,
                                               const float* __restrict__ S1,
                                               const float* __restrict__ EsAcc,
                                               const float* __restrict__ F1acc,
                                               const float* __restrict__ F2acc,
                                               float* __restrict__ out) {
    const int m = blockIdx.x;
    __shared__ float R[NATOMS * 3];
    __shared__ float FsL[NATOMS * 3];
    const int tid = threadIdx.x;
    if (tid < NATOMS * 3) {
        R[tid] = Rs[m * NATOMS * 3 + tid];
        FsL[tid] = 0.0f;
    }
    __syncthreads();
    if (tid < DESC) {
        int i, j;
        pair_ij(tid, i, j);
        const float dx = R[i * 3 + 0] - R[j * 3 + 0];
        const float dy = R[i * 3 + 1] - R[j * 3 + 1];
        const float dz = R[i * 3 + 2] - R[j * 3 + 2];
        const float r2 = dx * dx + dy * dy + dz * dz;
        const float rinv = 1.0f / sqrtf(r2);
        const float a = aT[tid * NM + m];  // q/r
        const float F1 = a * S1[m] - F1acc[m * DESC + tid];
        const float Fx = (F1 - F2acc[m * DESC + tid]) * STDC;
        const float coef = Fx * (rinv * rinv * rinv);
        atomicAdd(&FsL[j * 3 + 0], coef * dx);
        atomicAdd(&FsL[j * 3 + 1], coef * dy);
        atomicAdd(&FsL[j * 3 + 2], coef * dz);
        atomicAdd(&FsL[i * 3 + 0], -coef * dx);
        atomicAdd(&FsL[i * 3 + 1], -coef * dy);
        atomicAdd(&FsL[i * 3 + 2], -coef * dz);
    }
    __syncthreads();
    if (tid < NATOMS * 3) out[NM + m * NATOMS * 3 + tid] = FsL[tid];
    if (tid == 0) out[m] = CC + (EsAcc[m] / QS) * STDC;
}

extern "C" void kernel_launch(void* const* d_in, const int* in_sizes, int n_in,
                              void* d_out, int out_size, void* d_ws, size_t ws_size,
                              hipStream_t stream) {
    const float* Rs = (const float*)d_in[0];
    const float* xs_train = (const float*)d_in[1];
    const float* Jx = (const float*)d_in[2];
    float* out = (float*)d_out;
    float* ws = (float*)d_ws;

    // zeroed prefix
    float* F1acc = ws;                         // 26880
    float* F2acc = ws + 26880;                 // 26880
    float* EsAcc = ws + 53760;                 // 128
    float* S1 = ws + 53888;                    // 128
    float* bsqA = ws + 54016;                  // 4096
    float* cjA = ws + 58112;                   // 4096  -> zero block ends at 62208
    // non-zeroed
    float* aT = ws + 62208;                    // 224*128 = 28672
    float* asq = ws + 90880;                   // 128
    float4* bjq = (float4*)(ws + 91008);       // 112*4096 float4 (16B aligned)
    float2* w12 = (float2*)(ws + 1926016);     // 128*4096 float2 (16B aligned)
    float2* xj2 = (float2*)(ws + 2974592);     // 4096*256 float2 (16B aligned)
    // end 5071744 floats (~20.3 MB)

    hipMemsetAsync(ws, 0, (size_t)62208 * sizeof(float), stream);

    k_prep<<<576, 256, 0, stream>>>(Rs, xs_train, Jx, bjq, xj2, aT, asq, bsqA, cjA);
    k_pass1<<<512, 256, 0, stream>>>(bjq, aT, asq, bsqA, cjA, w12, EsAcc, S1);
    k_pass2<<<512, 256, 0, stream>>>(xj2, w12, F1acc, F2acc);
    k_final<<<NM, 256, 0, stream>>>(Rs, aT, S1, EsAcc, F1acc, F2acc, out);
}

// Round 11
// 69.580 us; speedup vs baseline: 8.2460x; 1.1255x over previous
//
#include <hip/hip_runtime.h>
#include <math.h>

#define NATOMS 21
#define DESC 210
#define DPAD 224          // padded descriptor count
#define P4 112            // DPAD/2 — float4-packed descriptor pairs
#define NTRAIN 4096
#define NM 128

#define CC 0.0f
#define STDC 1.0f
// q = sqrt(5)/sig
#define QS 0.22360679774997896f
// 5/(3*sig^2)
#define KE 0.016666666666666666f

// async global->LDS, 16B per lane, no VGPR round trip (guide §5 / T3)
__device__ __forceinline__ void gll16(const void* gptr, void* lptr) {
    __builtin_amdgcn_global_load_lds(
        (__attribute__((address_space(1))) void*)gptr,
        (__attribute__((address_space(3))) void*)lptr,
        16, 0, 0);
}

__device__ __forceinline__ void pair_ij(int p, int& i, int& j) {
    int ii = (int)((1.0f + sqrtf(1.0f + 8.0f * (float)p)) * 0.5f);
    while (ii * (ii - 1) / 2 > p) --ii;
    while ((ii + 1) * ii / 2 <= p) ++ii;
    i = ii;
    j = p - ii * (ii - 1) / 2;
}

// prep: blocks [0,448) transpose+pack xs/Jx into bjq (pass1) and xj2 (pass2),
//       accumulate bsq/cj per t; blocks [448,576) build aT, aP, asq.
__global__ __launch_bounds__(256, 2) void k_prep(const float* __restrict__ Rs,
                                                 const float* __restrict__ xs_train,
                                                 const float* __restrict__ Jx,
                                                 float4* __restrict__ bjq,
                                                 float2* __restrict__ xj2,
                                                 float* __restrict__ aT,
                                                 float* __restrict__ aPf,
                                                 float* __restrict__ asq,
                                                 float* __restrict__ bsqA,
                                                 float* __restrict__ cjA) {
    __shared__ float smem[2 * 32 * 65 + 8];
    const int tid = threadIdx.x;
    const int bid = blockIdx.x;
    if (bid < 448) {
        float* ldsX = smem;
        float* ldsJ = smem + 32 * 65;
        const int bx = bid & 63;        // t tile
        const int by = bid >> 6;        // d tile (0..6)
        const int t0 = bx * 64;
        const int d0 = by * 32;
        #pragma unroll
        for (int k = 0; k < 8; ++k) {
            const int idx = tid + k * 256;        // 64t x 32d
            const int tt = idx >> 5;
            const int dd = idx & 31;
            const int d = d0 + dd;
            float xv = 0.0f, jv = 0.0f;
            if (d < DESC) {
                xv = QS * xs_train[(t0 + tt) * DESC + d];
                jv = Jx[(t0 + tt) * DESC + d];
            }
            ldsX[dd * 65 + tt] = xv;
            ldsJ[dd * 65 + tt] = jv;
        }
        __syncthreads();
        #pragma unroll
        for (int k = 0; k < 4; ++k) {
            const int idx = tid + k * 256;        // 16p x 64t
            const int pp = idx >> 6;
            const int tt = idx & 63;
            float4 v;
            v.x = ldsX[(2 * pp) * 65 + tt];
            v.y = ldsJ[(2 * pp) * 65 + tt];
            v.z = ldsX[(2 * pp + 1) * 65 + tt];
            v.w = ldsJ[(2 * pp + 1) * 65 + tt];
            bjq[(by * 16 + pp) * NTRAIN + t0 + tt] = v;
        }
        // pass2 layout: xj2[t][256] = {q*xs, Jx}
        #pragma unroll
        for (int k = 0; k < 8; ++k) {
            const int idx = tid + k * 256;        // 64t x 32d
            const int tt = idx >> 5;
            const int dd = idx & 31;
            xj2[(t0 + tt) * 256 + d0 + dd] =
                make_float2(ldsX[dd * 65 + tt], ldsJ[dd * 65 + tt]);
        }
        // per-t partials of sum_d b^2 and sum_d b*j over this 32-d tile
        if (tid < 64) {
            float sb = 0.0f, sc = 0.0f;
            #pragma unroll
            for (int dd = 0; dd < 32; ++dd) {
                const float b = ldsX[dd * 65 + tid];
                const float jj = ldsJ[dd * 65 + tid];
                sb = fmaf(b, b, sb);
                sc = fmaf(b, jj, sc);
            }
            atomicAdd(&bsqA[t0 + tid], sb);
            atomicAdd(&cjA[t0 + tid], sc);
        }
    } else {
        const int m = bid - 448;
        float* R = smem;
        float* red = smem + 64;
        if (tid < NATOMS * 3) R[tid] = Rs[m * NATOMS * 3 + tid];
        __syncthreads();
        float a2 = 0.0f;
        if (tid < DPAD) {
            float a = 0.0f;
            if (tid < DESC) {
                int i, j;
                pair_ij(tid, i, j);
                const float dx = R[i * 3 + 0] - R[j * 3 + 0];
                const float dy = R[i * 3 + 1] - R[j * 3 + 1];
                const float dz = R[i * 3 + 2] - R[j * 3 + 2];
                a = QS / sqrtf(dx * dx + dy * dy + dz * dz);
            }
            aT[tid * NM + m] = a;
            // pass1 layout: aP[p][m] = {a(2p,m), a(2p+1,m)}
            aPf[(tid >> 1) * 256 + m * 2 + (tid & 1)] = a;
            a2 = a * a;
        }
        #pragma unroll
        for (int off = 32; off > 0; off >>= 1) a2 += __shfl_down(a2, off, 64);
        if ((tid & 63) == 0) red[tid >> 6] = a2;
        __syncthreads();
        if (tid == 0) asq[m] = red[0] + red[1] + red[2] + red[3];
    }
}

// pass 1 (lane = m): P[m,t] = sum_p a[p][m]·b, Q likewise. Each block owns 8 t
// (bjq read ONCE per element, wave-uniform b128 -> scalarizable); a read per-lane
// coalesced (114 KB total, L2-resident everywhere; re-read is free). No LDS
// staging, no barriers — TLP hides latency (4 waves/SIMD).
__global__ __launch_bounds__(256, 4) void k_pass1(const float4* __restrict__ bjq,
                                                  const float2* __restrict__ aP,
                                                  const float* __restrict__ asq,
                                                  const float* __restrict__ bsqA,
                                                  const float* __restrict__ cjA,
                                                  float2* __restrict__ w12T,
                                                  float* __restrict__ EsPart,
                                                  float* __restrict__ S1Part) {
    const int tid = threadIdx.x;
    const int bid = blockIdx.x;
    const int ml = tid & 127;
    const int tgu = __builtin_amdgcn_readfirstlane(tid >> 7);  // wave-uniform
    const int t0 = bid * 8 + tgu * 4;      // this group's 4 t columns

    float P[4] = {0.f, 0.f, 0.f, 0.f};
    float Q[4] = {0.f, 0.f, 0.f, 0.f};

    const float2* ap = aP + ml;            // + p*128
    const float4* bp = bjq + t0;           // + p*NTRAIN

    #pragma unroll 4
    for (int p = 0; p < P4; ++p) {
        const float2 a = ap[p * 128];                       // per-lane, coalesced
        const float4 b0 = bp[(size_t)p * NTRAIN + 0];       // wave-uniform
        const float4 b1 = bp[(size_t)p * NTRAIN + 1];
        const float4 b2 = bp[(size_t)p * NTRAIN + 2];
        const float4 b3 = bp[(size_t)p * NTRAIN + 3];
        P[0] = fmaf(a.x, b0.x, P[0]); P[0] = fmaf(a.y, b0.z, P[0]);
        Q[0] = fmaf(a.x, b0.y, Q[0]); Q[0] = fmaf(a.y, b0.w, Q[0]);
        P[1] = fmaf(a.x, b1.x, P[1]); P[1] = fmaf(a.y, b1.z, P[1]);
        Q[1] = fmaf(a.x, b1.y, Q[1]); Q[1] = fmaf(a.y, b1.w, Q[1]);
        P[2] = fmaf(a.x, b2.x, P[2]); P[2] = fmaf(a.y, b2.z, P[2]);
        Q[2] = fmaf(a.x, b2.y, Q[2]); Q[2] = fmaf(a.y, b2.w, Q[2]);
        P[3] = fmaf(a.x, b3.x, P[3]); P[3] = fmaf(a.y, b3.z, P[3]);
        Q[3] = fmaf(a.x, b3.y, Q[3]); Q[3] = fmaf(a.y, b3.w, Q[3]);
    }

    const float asqv = asq[ml];
    float es = 0.f, s1 = 0.f;
    #pragma unroll
    for (int j = 0; j < 4; ++j) {
        const int t = t0 + j;
        const float bsqv = bsqA[t];        // uniform
        const float cjv = cjA[t];          // uniform
        float dist2 = asqv + bsqv - 2.0f * P[j];
        dist2 = fmaxf(dist2, 0.0f);
        const float x = sqrtf(dist2);
        const float e = KE * expf(-x);
        const float dotv = Q[j] - cjv;
        const float w1v = e * dotv;
        const float w2v = e * (1.0f + x);
        w12T[t * NM + ml] = make_float2(w1v, w2v);   // coalesced
        es += w2v * dotv;
        s1 += w1v;
    }
    __shared__ float esL[2][128], s1L[2][128];
    esL[tgu][ml] = es;
    s1L[tgu][ml] = s1;
    __syncthreads();
    if (tid < 128) {
        EsPart[bid * NM + tid] = esL[0][tid] + esL[1][tid];
        S1Part[bid * NM + tid] = s1L[0][tid] + s1L[1][tid];
    }
}

// pass 2: counted-vmcnt 3-buffer pipeline (unchanged mechanism), w from w12T
// (t-major, linear gll16 stage). 256 threads (d = tid), 8 m, t-chunk 128.
__global__ __launch_bounds__(256, 2) void k_pass2(const float2* __restrict__ xj2,
                                                  const float2* __restrict__ w12T,
                                                  float* __restrict__ F1acc,
                                                  float* __restrict__ F2acc) {
    const int tid = threadIdx.x;
    const int bid = blockIdx.x;
    const int bx = (bid & 7) + 8 * (bid >> 7);   // t-tile 0..31
    const int my = (bid >> 3) & 15;              // m-group 0..15
    const int t0 = bx * 128;
    const int m0 = my * 8;

    __shared__ __align__(16) float2 wS2[128][8];       // 8 KB  [tt][mi] {w1,w2}
    __shared__ __align__(16) float2 xjS[3][8][256];    // 48 KB [buf][tt][d]

    // prologue: w-tile (2 gll16) + chunks 0,1 (4 gll16 each) -> 10 outstanding
    {
        // wS2 stage: f4 idx = tid + k*256; tb = idx>>2, mp = idx&3
        #pragma unroll
        for (int k = 0; k < 2; ++k) {
            const int idx = tid + k * 256;
            gll16(&w12T[(t0 + (idx >> 2)) * NM + m0 + 2 * (idx & 3)],
                  &reinterpret_cast<float4*>(wS2)[idx]);
        }
        const int row = tid >> 7;
        const int col = tid & 127;
        #pragma unroll
        for (int k = 0; k < 4; ++k)
            gll16(&xj2[(t0 + row + 2 * k) * 256 + 2 * col],
                  &xjS[0][row + 2 * k][2 * col]);
        #pragma unroll
        for (int k = 0; k < 4; ++k)
            gll16(&xj2[(t0 + 8 + row + 2 * k) * 256 + 2 * col],
                  &xjS[1][row + 2 * k][2 * col]);
    }

    const int d = (tid < DESC) ? tid : 0;
    float G1[8] = {0.f, 0.f, 0.f, 0.f, 0.f, 0.f, 0.f, 0.f};
    float G2[8] = {0.f, 0.f, 0.f, 0.f, 0.f, 0.f, 0.f, 0.f};

    for (int c = 0; c < 16; ++c) {
        if (c < 15) {
            asm volatile("s_waitcnt vmcnt(4) lgkmcnt(0)" ::: "memory");
        } else {
            asm volatile("s_waitcnt vmcnt(0) lgkmcnt(0)" ::: "memory");
        }
        __builtin_amdgcn_s_barrier();
        __builtin_amdgcn_sched_barrier(0);
        const float2* xjC = &xjS[c % 3][0][0];
        #pragma unroll
        for (int tt = 0; tt < 8; ++tt) {
            const int tb = c * 8 + tt;
            const float2 xj = xjC[tt * 256 + d];
            const float4 wa = *reinterpret_cast<const float4*>(&wS2[tb][0]);
            const float4 wb = *reinterpret_cast<const float4*>(&wS2[tb][2]);
            const float4 wc = *reinterpret_cast<const float4*>(&wS2[tb][4]);
            const float4 wd = *reinterpret_cast<const float4*>(&wS2[tb][6]);
            G1[0] = fmaf(wa.x, xj.x, G1[0]); G2[0] = fmaf(wa.y, xj.y, G2[0]);
            G1[1] = fmaf(wa.z, xj.x, G1[1]); G2[1] = fmaf(wa.w, xj.y, G2[1]);
            G1[2] = fmaf(wb.x, xj.x, G1[2]); G2[2] = fmaf(wb.y, xj.y, G2[2]);
            G1[3] = fmaf(wb.z, xj.x, G1[3]); G2[3] = fmaf(wb.w, xj.y, G2[3]);
            G1[4] = fmaf(wc.x, xj.x, G1[4]); G2[4] = fmaf(wc.y, xj.y, G2[4]);
            G1[5] = fmaf(wc.z, xj.x, G1[5]); G2[5] = fmaf(wc.w, xj.y, G2[5]);
            G1[6] = fmaf(wd.x, xj.x, G1[6]); G2[6] = fmaf(wd.y, xj.y, G2[6]);
            G1[7] = fmaf(wd.z, xj.x, G1[7]); G2[7] = fmaf(wd.w, xj.y, G2[7]);
        }
        if (c < 14) {
            const int row = tid >> 7;
            const int col = tid & 127;
            float2* dst = &xjS[(c + 2) % 3][0][0];
            #pragma unroll
            for (int k = 0; k < 4; ++k)
                gll16(&xj2[(t0 + (c + 2) * 8 + row + 2 * k) * 256 + 2 * col],
                      &dst[(row + 2 * k) * 256 + 2 * col]);
        }
    }

    if (tid < DESC) {
        #pragma unroll
        for (int mi = 0; mi < 8; ++mi) {
            atomicAdd(&F1acc[(m0 + mi) * DESC + tid], G1[mi]);
            atomicAdd(&F2acc[(m0 + mi) * DESC + tid], G2[mi]);
        }
    }
}

// final assembly — reduce Es/S1 partials, coef, force scatter, Es
__global__ __launch_bounds__(256) void k_final(const float* __restrict__ Rs,
                                               const float* __restrict__ aT,
                                               const float* __restrict__ EsPart,
                                               const float* __restrict__ S1Part,
                                               const float* __restrict__ F1acc,
                                               const float* __restrict__ F2acc,
                                               float* __restrict__ out) {
    const int m = blockIdx.x;
    __shared__ float R[NATOMS * 3];
    __shared__ float FsL[NATOMS * 3];
    __shared__ float redE[4], redS[4];
    __shared__ float sEs, sS1;
    const int tid = threadIdx.x;
    // reduce 512 partials for this molecule
    float esp = EsPart[tid * NM + m] + EsPart[(tid + 256) * NM + m];
    float s1p = S1Part[tid * NM + m] + S1Part[(tid + 256) * NM + m];
    #pragma unroll
    for (int off = 32; off > 0; off >>= 1) {
        esp += __shfl_down(esp, off, 64);
        s1p += __shfl_down(s1p, off, 64);
    }
    if ((tid & 63) == 0) { redE[tid >> 6] = esp; redS[tid >> 6] = s1p; }
    if (tid < NATOMS * 3) {
        R[tid] = Rs[m * NATOMS * 3 + tid];
        FsL[tid] = 0.0f;
    }
    __syncthreads();
    if (tid == 0) {
        sEs = redE[0] + redE[1] + redE[2] + redE[3];
        sS1 = redS[0] + redS[1] + redS[2] + redS[3];
    }
    __syncthreads();
    if (tid < DESC) {
        int i, j;
        pair_ij(tid, i, j);
        const float dx = R[i * 3 + 0] - R[j * 3 + 0];
        const float dy = R[i * 3 + 1] - R[j * 3 + 1];
        const float dz = R[i * 3 + 2] - R[j * 3 + 2];
        const float r2 = dx * dx + dy * dy + dz * dz;
        const float rinv = 1.0f / sqrtf(r2);
        const float a = aT[tid * NM + m];  // q/r
        const float F1 = a * sS1 - F1acc[m * DESC + tid];
        const float Fx = (F1 - F2acc[m * DESC + tid]) * STDC;
        const float coef = Fx * (rinv * rinv * rinv);
        atomicAdd(&FsL[j * 3 + 0], coef * dx);
        atomicAdd(&FsL[j * 3 + 1], coef * dy);
        atomicAdd(&FsL[j * 3 + 2], coef * dz);
        atomicAdd(&FsL[i * 3 + 0], -coef * dx);
        atomicAdd(&FsL[i * 3 + 1], -coef * dy);
        atomicAdd(&FsL[i * 3 + 2], -coef * dz);
    }
    __syncthreads();
    if (tid < NATOMS * 3) out[NM + m * NATOMS * 3 + tid] = FsL[tid];
    if (tid == 0) out[m] = CC + (sEs / QS) * STDC;
}

extern "C" void kernel_launch(void* const* d_in, const int* in_sizes, int n_in,
                              void* d_out, int out_size, void* d_ws, size_t ws_size,
                              hipStream_t stream) {
    const float* Rs = (const float*)d_in[0];
    const float* xs_train = (const float*)d_in[1];
    const float* Jx = (const float*)d_in[2];
    float* out = (float*)d_out;
    float* ws = (float*)d_ws;

    // zeroed prefix
    float* F1acc = ws;                         // 26880
    float* F2acc = ws + 26880;                 // 26880
    float* bsqA = ws + 53760;                  // 4096
    float* cjA = ws + 57856;                   // 4096  -> zero block ends at 61952
    // non-zeroed
    float* aT = ws + 61952;                    // 224*128 = 28672
    float* asq = ws + 90624;                   // 128
    float* aPf = ws + 90752;                   // 112*128*2 = 28672
    float* EsPart = ws + 119424;               // 512*128 = 65536
    float* S1Part = ws + 184960;               // 65536
    float4* bjq = (float4*)(ws + 250496);      // 112*4096 float4 (16B aligned)
    float2* w12T = (float2*)(ws + 2085504);    // 4096*128 float2
    float2* xj2 = (float2*)(ws + 3134080);     // 4096*256 float2
    // end 5231232 floats (~20.9 MB)

    hipMemsetAsync(ws, 0, (size_t)61952 * sizeof(float), stream);

    k_prep<<<576, 256, 0, stream>>>(Rs, xs_train, Jx, bjq, xj2, aT, aPf, asq,
                                    bsqA, cjA);
    k_pass1<<<512, 256, 0, stream>>>(bjq, (const float2*)aPf, asq, bsqA, cjA,
                                     w12T, EsPart, S1Part);
    k_pass2<<<512, 256, 0, stream>>>(xj2, w12T, F1acc, F2acc);
    k_final<<<NM, 256, 0, stream>>>(Rs, aT, EsPart, S1Part, F1acc, F2acc, out);
}

// Round 12
// 64.820 us; speedup vs baseline: 8.8514x; 1.0734x over previous
//
#include <hip/hip_runtime.h>
#include <math.h>

#define NATOMS 21
#define DESC 210
#define DPAD 224          // padded descriptor count
#define P4 112            // DPAD/2 — float4-packed descriptor pairs
#define NTRAIN 4096
#define NM 128

#define CC 0.0f
#define STDC 1.0f
// q = sqrt(5)/sig
#define QS 0.22360679774997896f
// 5/(3*sig^2)
#define KE 0.016666666666666666f

// async global->LDS, 16B per lane, no VGPR round trip (guide §5 / T3)
__device__ __forceinline__ void gll16(const void* gptr, void* lptr) {
    __builtin_amdgcn_global_load_lds(
        (__attribute__((address_space(1))) void*)gptr,
        (__attribute__((address_space(3))) void*)lptr,
        16, 0, 0);
}

__device__ __forceinline__ void pair_ij(int p, int& i, int& j) {
    int ii = (int)((1.0f + sqrtf(1.0f + 8.0f * (float)p)) * 0.5f);
    while (ii * (ii - 1) / 2 > p) --ii;
    while ((ii + 1) * ii / 2 <= p) ++ii;
    i = ii;
    j = p - ii * (ii - 1) / 2;
}

// prep: blocks [0,448) transpose+pack xs/Jx into bjq (pass1) and xj2 (pass2),
//       store per-d-tile partials of bsq/cj (NO atomics); blocks [448,576)
//       build aT, aP, asq. ALSO zeros F1acc/F2acc (replaces hipMemsetAsync,
//       which cost 40 us/replay as a fill dispatch — R11 profile).
__global__ __launch_bounds__(256, 2) void k_prep(const float* __restrict__ Rs,
                                                 const float* __restrict__ xs_train,
                                                 const float* __restrict__ Jx,
                                                 float4* __restrict__ bjq,
                                                 float2* __restrict__ xj2,
                                                 float* __restrict__ aT,
                                                 float* __restrict__ aPf,
                                                 float* __restrict__ asq,
                                                 float* __restrict__ bsqPart,
                                                 float* __restrict__ cjPart,
                                                 float* __restrict__ Fzero) {
    __shared__ float smem[2 * 32 * 65 + 8];
    const int tid = threadIdx.x;
    const int bid = blockIdx.x;
    // zero the atomic accumulators (53760 floats over 576 blocks x 256 threads)
    {
        const int z = bid * 256 + tid;
        if (z < 2 * 26880) Fzero[z] = 0.0f;
    }
    if (bid < 448) {
        float* ldsX = smem;
        float* ldsJ = smem + 32 * 65;
        const int bx = bid & 63;        // t tile
        const int by = bid >> 6;        // d tile (0..6)
        const int t0 = bx * 64;
        const int d0 = by * 32;
        #pragma unroll
        for (int k = 0; k < 8; ++k) {
            const int idx = tid + k * 256;        // 64t x 32d
            const int tt = idx >> 5;
            const int dd = idx & 31;
            const int d = d0 + dd;
            float xv = 0.0f, jv = 0.0f;
            if (d < DESC) {
                xv = QS * xs_train[(t0 + tt) * DESC + d];
                jv = Jx[(t0 + tt) * DESC + d];
            }
            ldsX[dd * 65 + tt] = xv;
            ldsJ[dd * 65 + tt] = jv;
        }
        __syncthreads();
        #pragma unroll
        for (int k = 0; k < 4; ++k) {
            const int idx = tid + k * 256;        // 16p x 64t
            const int pp = idx >> 6;
            const int tt = idx & 63;
            float4 v;
            v.x = ldsX[(2 * pp) * 65 + tt];
            v.y = ldsJ[(2 * pp) * 65 + tt];
            v.z = ldsX[(2 * pp + 1) * 65 + tt];
            v.w = ldsJ[(2 * pp + 1) * 65 + tt];
            bjq[(by * 16 + pp) * NTRAIN + t0 + tt] = v;
        }
        // pass2 layout: xj2[t][256] = {q*xs, Jx}
        #pragma unroll
        for (int k = 0; k < 8; ++k) {
            const int idx = tid + k * 256;        // 64t x 32d
            const int tt = idx >> 5;
            const int dd = idx & 31;
            xj2[(t0 + tt) * 256 + d0 + dd] =
                make_float2(ldsX[dd * 65 + tt], ldsJ[dd * 65 + tt]);
        }
        // per-t partials of sum_d b^2 and sum_d b*j over this 32-d tile
        if (tid < 64) {
            float sb = 0.0f, sc = 0.0f;
            #pragma unroll
            for (int dd = 0; dd < 32; ++dd) {
                const float b = ldsX[dd * 65 + tid];
                const float jj = ldsJ[dd * 65 + tid];
                sb = fmaf(b, b, sb);
                sc = fmaf(b, jj, sc);
            }
            bsqPart[by * NTRAIN + t0 + tid] = sb;   // plain store, no atomic
            cjPart[by * NTRAIN + t0 + tid] = sc;
        }
    } else {
        const int m = bid - 448;
        float* R = smem;
        float* red = smem + 64;
        if (tid < NATOMS * 3) R[tid] = Rs[m * NATOMS * 3 + tid];
        __syncthreads();
        float a2 = 0.0f;
        if (tid < DPAD) {
            float a = 0.0f;
            if (tid < DESC) {
                int i, j;
                pair_ij(tid, i, j);
                const float dx = R[i * 3 + 0] - R[j * 3 + 0];
                const float dy = R[i * 3 + 1] - R[j * 3 + 1];
                const float dz = R[i * 3 + 2] - R[j * 3 + 2];
                a = QS / sqrtf(dx * dx + dy * dy + dz * dz);
            }
            aT[tid * NM + m] = a;
            // pass1 layout: aP[p][m] = {a(2p,m), a(2p+1,m)}
            aPf[(tid >> 1) * 256 + m * 2 + (tid & 1)] = a;
            a2 = a * a;
        }
        #pragma unroll
        for (int off = 32; off > 0; off >>= 1) a2 += __shfl_down(a2, off, 64);
        if ((tid & 63) == 0) red[tid >> 6] = a2;
        __syncthreads();
        if (tid == 0) asq[m] = red[0] + red[1] + red[2] + red[3];
    }
}

// pass 1 (lane = m): P[m,t] = sum_p a[p][m]·b, Q likewise. Each block owns 8 t
// (bjq read ONCE per element, wave-uniform b128 -> scalarizable); a read per-lane
// coalesced. No staging, no barriers — TLP hides latency (4 waves/SIMD).
__global__ __launch_bounds__(256, 4) void k_pass1(const float4* __restrict__ bjq,
                                                  const float2* __restrict__ aP,
                                                  const float* __restrict__ asq,
                                                  const float* __restrict__ bsqPart,
                                                  const float* __restrict__ cjPart,
                                                  float2* __restrict__ w12T,
                                                  float* __restrict__ EsPart,
                                                  float* __restrict__ S1Part) {
    const int tid = threadIdx.x;
    const int bid = blockIdx.x;
    const int ml = tid & 127;
    const int tgu = __builtin_amdgcn_readfirstlane(tid >> 7);  // wave-uniform
    const int t0 = bid * 8 + tgu * 4;      // this group's 4 t columns

    float P[4] = {0.f, 0.f, 0.f, 0.f};
    float Q[4] = {0.f, 0.f, 0.f, 0.f};

    const float2* ap = aP + ml;            // + p*128
    const float4* bp = bjq + t0;           // + p*NTRAIN

    #pragma unroll 4
    for (int p = 0; p < P4; ++p) {
        const float2 a = ap[p * 128];                       // per-lane, coalesced
        const float4 b0 = bp[(size_t)p * NTRAIN + 0];       // wave-uniform
        const float4 b1 = bp[(size_t)p * NTRAIN + 1];
        const float4 b2 = bp[(size_t)p * NTRAIN + 2];
        const float4 b3 = bp[(size_t)p * NTRAIN + 3];
        P[0] = fmaf(a.x, b0.x, P[0]); P[0] = fmaf(a.y, b0.z, P[0]);
        Q[0] = fmaf(a.x, b0.y, Q[0]); Q[0] = fmaf(a.y, b0.w, Q[0]);
        P[1] = fmaf(a.x, b1.x, P[1]); P[1] = fmaf(a.y, b1.z, P[1]);
        Q[1] = fmaf(a.x, b1.y, Q[1]); Q[1] = fmaf(a.y, b1.w, Q[1]);
        P[2] = fmaf(a.x, b2.x, P[2]); P[2] = fmaf(a.y, b2.z, P[2]);
        Q[2] = fmaf(a.x, b2.y, Q[2]); Q[2] = fmaf(a.y, b2.w, Q[2]);
        P[3] = fmaf(a.x, b3.x, P[3]); P[3] = fmaf(a.y, b3.z, P[3]);
        Q[3] = fmaf(a.x, b3.y, Q[3]); Q[3] = fmaf(a.y, b3.w, Q[3]);
    }

    const float asqv = asq[ml];
    float es = 0.f, s1 = 0.f;
    #pragma unroll
    for (int j = 0; j < 4; ++j) {
        const int t = t0 + j;
        float bsqv = 0.f, cjv = 0.f;
        #pragma unroll
        for (int by = 0; by < 7; ++by) {   // sum prep's per-d-tile partials (uniform)
            bsqv += bsqPart[by * NTRAIN + t];
            cjv += cjPart[by * NTRAIN + t];
        }
        float dist2 = asqv + bsqv - 2.0f * P[j];
        dist2 = fmaxf(dist2, 0.0f);
        const float x = sqrtf(dist2);
        const float e = KE * expf(-x);
        const float dotv = Q[j] - cjv;
        const float w1v = e * dotv;
        const float w2v = e * (1.0f + x);
        w12T[t * NM + ml] = make_float2(w1v, w2v);   // coalesced
        es += w2v * dotv;
        s1 += w1v;
    }
    __shared__ float esL[2][128], s1L[2][128];
    esL[tgu][ml] = es;
    s1L[tgu][ml] = s1;
    __syncthreads();
    if (tid < 128) {
        EsPart[bid * NM + tid] = esL[0][tid] + esL[1][tid];
        S1Part[bid * NM + tid] = s1L[0][tid] + s1L[1][tid];
    }
}

// pass 2: counted-vmcnt 3-buffer pipeline, w from w12T (t-major, linear gll16
// stage). 256 threads (d = tid), 8 m, t-chunk 128.
__global__ __launch_bounds__(256, 2) void k_pass2(const float2* __restrict__ xj2,
                                                  const float2* __restrict__ w12T,
                                                  float* __restrict__ F1acc,
                                                  float* __restrict__ F2acc) {
    const int tid = threadIdx.x;
    const int bid = blockIdx.x;
    const int bx = (bid & 7) + 8 * (bid >> 7);   // t-tile 0..31
    const int my = (bid >> 3) & 15;              // m-group 0..15
    const int t0 = bx * 128;
    const int m0 = my * 8;

    __shared__ __align__(16) float2 wS2[128][8];       // 8 KB  [tt][mi] {w1,w2}
    __shared__ __align__(16) float2 xjS[3][8][256];    // 48 KB [buf][tt][d]

    // prologue: w-tile (2 gll16) + chunks 0,1 (4 gll16 each) -> 10 outstanding
    {
        #pragma unroll
        for (int k = 0; k < 2; ++k) {
            const int idx = tid + k * 256;
            gll16(&w12T[(t0 + (idx >> 2)) * NM + m0 + 2 * (idx & 3)],
                  &reinterpret_cast<float4*>(wS2)[idx]);
        }
        const int row = tid >> 7;
        const int col = tid & 127;
        #pragma unroll
        for (int k = 0; k < 4; ++k)
            gll16(&xj2[(t0 + row + 2 * k) * 256 + 2 * col],
                  &xjS[0][row + 2 * k][2 * col]);
        #pragma unroll
        for (int k = 0; k < 4; ++k)
            gll16(&xj2[(t0 + 8 + row + 2 * k) * 256 + 2 * col],
                  &xjS[1][row + 2 * k][2 * col]);
    }

    const int d = (tid < DESC) ? tid : 0;
    float G1[8] = {0.f, 0.f, 0.f, 0.f, 0.f, 0.f, 0.f, 0.f};
    float G2[8] = {0.f, 0.f, 0.f, 0.f, 0.f, 0.f, 0.f, 0.f};

    for (int c = 0; c < 16; ++c) {
        if (c < 15) {
            asm volatile("s_waitcnt vmcnt(4) lgkmcnt(0)" ::: "memory");
        } else {
            asm volatile("s_waitcnt vmcnt(0) lgkmcnt(0)" ::: "memory");
        }
        __builtin_amdgcn_s_barrier();
        __builtin_amdgcn_sched_barrier(0);
        const float2* xjC = &xjS[c % 3][0][0];
        #pragma unroll
        for (int tt = 0; tt < 8; ++tt) {
            const int tb = c * 8 + tt;
            const float2 xj = xjC[tt * 256 + d];
            const float4 wa = *reinterpret_cast<const float4*>(&wS2[tb][0]);
            const float4 wb = *reinterpret_cast<const float4*>(&wS2[tb][2]);
            const float4 wc = *reinterpret_cast<const float4*>(&wS2[tb][4]);
            const float4 wd = *reinterpret_cast<const float4*>(&wS2[tb][6]);
            G1[0] = fmaf(wa.x, xj.x, G1[0]); G2[0] = fmaf(wa.y, xj.y, G2[0]);
            G1[1] = fmaf(wa.z, xj.x, G1[1]); G2[1] = fmaf(wa.w, xj.y, G2[1]);
            G1[2] = fmaf(wb.x, xj.x, G1[2]); G2[2] = fmaf(wb.y, xj.y, G2[2]);
            G1[3] = fmaf(wb.z, xj.x, G1[3]); G2[3] = fmaf(wb.w, xj.y, G2[3]);
            G1[4] = fmaf(wc.x, xj.x, G1[4]); G2[4] = fmaf(wc.y, xj.y, G2[4]);
            G1[5] = fmaf(wc.z, xj.x, G1[5]); G2[5] = fmaf(wc.w, xj.y, G2[5]);
            G1[6] = fmaf(wd.x, xj.x, G1[6]); G2[6] = fmaf(wd.y, xj.y, G2[6]);
            G1[7] = fmaf(wd.z, xj.x, G1[7]); G2[7] = fmaf(wd.w, xj.y, G2[7]);
        }
        if (c < 14) {
            const int row = tid >> 7;
            const int col = tid & 127;
            float2* dst = &xjS[(c + 2) % 3][0][0];
            #pragma unroll
            for (int k = 0; k < 4; ++k)
                gll16(&xj2[(t0 + (c + 2) * 8 + row + 2 * k) * 256 + 2 * col],
                      &dst[(row + 2 * k) * 256 + 2 * col]);
        }
    }

    if (tid < DESC) {
        #pragma unroll
        for (int mi = 0; mi < 8; ++mi) {
            atomicAdd(&F1acc[(m0 + mi) * DESC + tid], G1[mi]);
            atomicAdd(&F2acc[(m0 + mi) * DESC + tid], G2[mi]);
        }
    }
}

// final assembly — reduce Es/S1 partials, coef, force scatter, Es
__global__ __launch_bounds__(256) void k_final(const float* __restrict__ Rs,
                                               const float* __restrict__ aT,
                                               const float* __restrict__ EsPart,
                                               const float* __restrict__ S1Part,
                                               const float* __restrict__ F1acc,
                                               const float* __restrict__ F2acc,
                                               float* __restrict__ out) {
    const int m = blockIdx.x;
    __shared__ float R[NATOMS * 3];
    __shared__ float FsL[NATOMS * 3];
    __shared__ float redE[4], redS[4];
    __shared__ float sEs, sS1;
    const int tid = threadIdx.x;
    // reduce 512 partials for this molecule
    float esp = EsPart[tid * NM + m] + EsPart[(tid + 256) * NM + m];
    float s1p = S1Part[tid * NM + m] + S1Part[(tid + 256) * NM + m];
    #pragma unroll
    for (int off = 32; off > 0; off >>= 1) {
        esp += __shfl_down(esp, off, 64);
        s1p += __shfl_down(s1p, off, 64);
    }
    if ((tid & 63) == 0) { redE[tid >> 6] = esp; redS[tid >> 6] = s1p; }
    if (tid < NATOMS * 3) {
        R[tid] = Rs[m * NATOMS * 3 + tid];
        FsL[tid] = 0.0f;
    }
    __syncthreads();
    if (tid == 0) {
        sEs = redE[0] + redE[1] + redE[2] + redE[3];
        sS1 = redS[0] + redS[1] + redS[2] + redS[3];
    }
    __syncthreads();
    if (tid < DESC) {
        int i, j;
        pair_ij(tid, i, j);
        const float dx = R[i * 3 + 0] - R[j * 3 + 0];
        const float dy = R[i * 3 + 1] - R[j * 3 + 1];
        const float dz = R[i * 3 + 2] - R[j * 3 + 2];
        const float r2 = dx * dx + dy * dy + dz * dz;
        const float rinv = 1.0f / sqrtf(r2);
        const float a = aT[tid * NM + m];  // q/r
        const float F1 = a * sS1 - F1acc[m * DESC + tid];
        const float Fx = (F1 - F2acc[m * DESC + tid]) * STDC;
        const float coef = Fx * (rinv * rinv * rinv);
        atomicAdd(&FsL[j * 3 + 0], coef * dx);
        atomicAdd(&FsL[j * 3 + 1], coef * dy);
        atomicAdd(&FsL[j * 3 + 2], coef * dz);
        atomicAdd(&FsL[i * 3 + 0], -coef * dx);
        atomicAdd(&FsL[i * 3 + 1], -coef * dy);
        atomicAdd(&FsL[i * 3 + 2], -coef * dz);
    }
    __syncthreads();
    if (tid < NATOMS * 3) out[NM + m * NATOMS * 3 + tid] = FsL[tid];
    if (tid == 0) out[m] = CC + (sEs / QS) * STDC;
}

extern "C" void kernel_launch(void* const* d_in, const int* in_sizes, int n_in,
                              void* d_out, int out_size, void* d_ws, size_t ws_size,
                              hipStream_t stream) {
    const float* Rs = (const float*)d_in[0];
    const float* xs_train = (const float*)d_in[1];
    const float* Jx = (const float*)d_in[2];
    float* out = (float*)d_out;
    float* ws = (float*)d_ws;

    float* F1acc = ws;                         // 26880 (zeroed by k_prep)
    float* F2acc = ws + 26880;                 // 26880 (zeroed by k_prep)
    float* bsqPart = ws + 53760;               // 7*4096 = 28672 (plain stores)
    float* cjPart = ws + 82432;                // 28672
    float* aT = ws + 111104;                   // 224*128 = 28672
    float* asq = ws + 139776;                  // 128
    float* aPf = ws + 139904;                  // 28672
    float* EsPart = ws + 168576;               // 512*128 = 65536
    float* S1Part = ws + 234112;               // 65536
    float4* bjq = (float4*)(ws + 299648);      // 112*4096 float4 (16B aligned)
    float2* w12T = (float2*)(ws + 2134656);    // 4096*128 float2
    float2* xj2 = (float2*)(ws + 3183232);     // 4096*256 float2
    // end 5280384 floats (~21.1 MB)

    k_prep<<<576, 256, 0, stream>>>(Rs, xs_train, Jx, bjq, xj2, aT, aPf, asq,
                                    bsqPart, cjPart, F1acc);
    k_pass1<<<512, 256, 0, stream>>>(bjq, (const float2*)aPf, asq, bsqPart, cjPart,
                                     w12T, EsPart, S1Part);
    k_pass2<<<512, 256, 0, stream>>>(xj2, w12T, F1acc, F2acc);
    k_final<<<NM, 256, 0, stream>>>(Rs, aT, EsPart, S1Part, F1acc, F2acc, out);
}